// Round 2
// baseline (29.499 us; speedup 1.0000x reference)
//
#include <hip/hip_runtime.h>

#define IMG   512
#define NCLS  256
#define DIM   1024
#define HPW   32            // patches per side
#define PPB   16            // tokens per block: 2 patch-rows x 8 patch-cols
#define NT    512           // threads per block (8 waves)

typedef short bf16x8 __attribute__((ext_vector_type(8)));   // 8 bf16 in 4 VGPRs
typedef float f32x4  __attribute__((ext_vector_type(4)));

__device__ inline ushort f32_to_bf16_rne(float v) {
    unsigned u = __float_as_uint(v);
    unsigned r = u + 0x7fffu + ((u >> 16) & 1u);
    return (ushort)(r >> 16);
}

// ---------- prep: table f32 [256][1024] -> Tt bf16 [1024][256] (transposed) ----------
__global__ __launch_bounds__(256)
void transpose_table(const float* __restrict__ table, ushort* __restrict__ Tt)
{
    __shared__ ushort tile[64][66];          // 66*2B=132B row stride -> conflict-free-ish
    const int c0 = blockIdx.x * 64;          // class tile
    const int d0 = blockIdx.y * 64;          // dim tile
    const int t  = threadIdx.x;

    #pragma unroll
    for (int it = 0; it < 16; ++it) {
        const int idx = it * 256 + t;
        const int cl  = idx >> 6, dl = idx & 63;          // read coalesced along dims
        const float v = table[(size_t)(c0 + cl) * DIM + d0 + dl];
        tile[dl][cl] = f32_to_bf16_rne(v);
    }
    __syncthreads();
    #pragma unroll
    for (int it = 0; it < 16; ++it) {
        const int idx = it * 256 + t;
        const int dl  = idx >> 6, cl = idx & 63;          // write coalesced along classes
        Tt[(size_t)(d0 + dl) * NCLS + c0 + cl] = tile[dl][cl];
    }
}

// ---------- main: hist -> MFMA GEMM (16 x 1024 x 256) -> +pos -> LN -> out ----------
__global__ __launch_bounds__(NT)
void semtok_mfma(const int* __restrict__ smap, const ushort* __restrict__ Tt,
                 const float* __restrict__ gamma, const float* __restrict__ beta,
                 float* __restrict__ out)
{
    __shared__ unsigned cnt[PPB * NCLS];     // 16 KB histogram
    __shared__ ushort  cntb[PPB][264];       // bf16 counts/256, padded stride
    __shared__ float   red[8][4][4][2];      // [wave][lane-group][i][{s,s2}]

    const int t    = threadIdx.x;
    const int lane = t & 63;
    const int w    = t >> 6;                 // wave id: owns dims [w*128, w*128+128)
    const int c    = lane & 15;              // MFMA col / A-row selector
    const int g    = lane >> 4;              // MFMA k-group / D-row group

    const int pw0 = blockIdx.x * 8;          // 8 patch-cols
    const int ph0 = blockIdx.y * 2;          // 2 patch-rows
    const int b   = blockIdx.z;

    // ---- phase 1: zero + histogram over 32x128 pixel region (4096 px) ----
    for (int i = t; i < PPB * NCLS; i += NT) cnt[i] = 0u;
    __syncthreads();

    const int* base = smap + ((size_t)b * IMG + (size_t)ph0 * 16) * IMG + (size_t)pw0 * 16;
    #pragma unroll
    for (int it = 0; it < 2; ++it) {
        const int pix = (it * NT + t) * 4;
        const int row = pix >> 7;            // 0..31
        const int col = pix & 127;
        const int4 q = *reinterpret_cast<const int4*>(base + (size_t)row * IMG + col);
        unsigned* hp = &cnt[((row >> 4) * 8 + (col >> 4)) * NCLS];
        atomicAdd(&hp[min(max(q.x, 0), NCLS - 1)], 1u);
        atomicAdd(&hp[min(max(q.y, 0), NCLS - 1)], 1u);
        atomicAdd(&hp[min(max(q.z, 0), NCLS - 1)], 1u);
        atomicAdd(&hp[min(max(q.w, 0), NCLS - 1)], 1u);
    }
    __syncthreads();

    // ---- phase 2: counts -> bf16(count/256) (exact: <=8 significant bits) ----
    for (int i = t; i < PPB * NCLS; i += NT) {
        const float f = (float)cnt[i] * (1.0f / 256.0f);
        cntb[i >> 8][i & 255] = (ushort)(__float_as_uint(f) >> 16); // low bits are zero
    }
    __syncthreads();

    // ---- phase 3: MFMA K-loop: acc[tt] (16 tokens x 16 dims), tt = dim tile ----
    f32x4 acc[8];
    #pragma unroll
    for (int i = 0; i < 8; ++i) acc[i] = (f32x4){0.f, 0.f, 0.f, 0.f};

    const ushort* tbase = Tt + (size_t)(w * 128 + c) * NCLS + g * 8;  // Tt[dim][class]
    const ushort* abase = &cntb[c][g * 8];

    #pragma unroll
    for (int ks = 0; ks < 8; ++ks) {
        const bf16x8 a = *reinterpret_cast<const bf16x8*>(abase + ks * 32);
        #pragma unroll
        for (int tt = 0; tt < 8; ++tt) {
            const bf16x8 bf = *reinterpret_cast<const bf16x8*>(tbase + (size_t)tt * 16 * NCLS + ks * 32);
            acc[tt] = __builtin_amdgcn_mfma_f32_16x16x32_bf16(a, bf, acc[tt], 0, 0, 0);
        }
    }

    // ---- phase 4: += sincos pos-embed; per-lane LN partials ----
    // D layout: row r = g*4+i (token), col = c, dim d = w*128 + tt*16 + c
    // token r: ph = ph0 + (r>>3), pw = pw0 + (r&7);  r>>3 == g>>1, r&7 == (g&1)*4+i
    const int  cosSel = (w >> 1) & 1;        // quads 1,3 use cos
    float ls[4]  = {0.f, 0.f, 0.f, 0.f};
    float ls2[4] = {0.f, 0.f, 0.f, 0.f};

    #pragma unroll
    for (int tt = 0; tt < 8; ++tt) {
        const int d = w * 128 + tt * 16 + c;
        const float omega = exp2f((float)(d & 255) * (-13.287712379549449f / 256.0f));
        if (w < 4) {                         // h-embed: same for all 4 tokens of this lane
            float sv, cv;
            __sincosf((float)(ph0 + (g >> 1)) * omega, &sv, &cv);
            const float v = cosSel ? cv : sv;
            #pragma unroll
            for (int i = 0; i < 4; ++i) acc[tt][i] += v;
        } else {                             // w-embed: depends on token's pw
            #pragma unroll
            for (int i = 0; i < 4; ++i) {
                float sv, cv;
                __sincosf((float)(pw0 + (g & 1) * 4 + i) * omega, &sv, &cv);
                acc[tt][i] += cosSel ? cv : sv;
            }
        }
        #pragma unroll
        for (int i = 0; i < 4; ++i) {
            ls[i]  += acc[tt][i];
            ls2[i] += acc[tt][i] * acc[tt][i];
        }
    }

    // reduce across the 16 lanes of each k-group (they hold the same 4 tokens)
    #pragma unroll
    for (int off = 1; off < 16; off <<= 1) {
        #pragma unroll
        for (int i = 0; i < 4; ++i) {
            ls[i]  += __shfl_xor(ls[i],  off, 64);
            ls2[i] += __shfl_xor(ls2[i], off, 64);
        }
    }
    if (c == 0) {
        #pragma unroll
        for (int i = 0; i < 4; ++i) { red[w][g][i][0] = ls[i]; red[w][g][i][1] = ls2[i]; }
    }
    __syncthreads();

    // ---- phase 5: finalize LN, scale, store ----
    float mu[4], rs[4];
    #pragma unroll
    for (int i = 0; i < 4; ++i) {
        float S = 0.f, S2 = 0.f;
        #pragma unroll
        for (int ww = 0; ww < 8; ++ww) { S += red[ww][g][i][0]; S2 += red[ww][g][i][1]; }
        mu[i] = S * (1.0f / DIM);
        rs[i] = rsqrtf(S2 * (1.0f / DIM) - mu[i] * mu[i] + 1e-5f);
    }

    #pragma unroll
    for (int tt = 0; tt < 8; ++tt) {
        const int d = w * 128 + tt * 16 + c;
        const float gv = gamma[d], bv = beta[d];
        #pragma unroll
        for (int i = 0; i < 4; ++i) {
            const int r     = g * 4 + i;
            const int token = (ph0 + (r >> 3)) * HPW + pw0 + (r & 7);
            out[((size_t)b * (HPW * HPW) + token) * DIM + d] =
                (acc[tt][i] - mu[i]) * rs[i] * gv + bv;
        }
    }
}

extern "C" void kernel_launch(void* const* d_in, const int* in_sizes, int n_in,
                              void* d_out, int out_size, void* d_ws, size_t ws_size,
                              hipStream_t stream) {
    const int*   smap  = (const int*)d_in[0];
    const float* table = (const float*)d_in[1];
    const float* gamma = (const float*)d_in[2];
    const float* beta  = (const float*)d_in[3];
    float*       out   = (float*)d_out;
    ushort*      Tt    = (ushort*)d_ws;                    // 1024*256*2 B = 512 KB

    const int batches = in_sizes[0] / (IMG * IMG);

    dim3 tgrid(NCLS / 64, DIM / 64);                       // (4, 16)
    transpose_table<<<tgrid, 256, 0, stream>>>(table, Tt);

    dim3 grid(HPW / 8, HPW / 2, batches);                  // (4, 16, 2)
    semtok_mfma<<<grid, NT, 0, stream>>>(smap, Tt, gamma, beta, out);
}